// Round 13
// baseline (306.316 us; speedup 1.0000x reference)
//
#include <hip/hip_runtime.h>
#include <hip/hip_bf16.h>

// Shapes (hardcoded from reference): C=4, B=2, BC=8, HEADS=24, DH=64, D=1536,
// CROSS=2048, S=2048, E=PAD=77. Output f32 [8,2048,1536].

typedef __attribute__((ext_vector_type(8))) short short8;
typedef __attribute__((ext_vector_type(4))) float f32x4;
typedef __attribute__((ext_vector_type(4))) _Float16 half4;

#define DEV __device__ __forceinline__

DEV ushort f2bf(float x) {
  __hip_bfloat16 h = __float2bfloat16(x);
  return *reinterpret_cast<ushort*>(&h);
}

// ---------------- merged conversion kernel ----------------

__global__ __launch_bounds__(256) void cvt_all(const float* __restrict__ hs, ushort* __restrict__ hs_bf,
                                               const float* __restrict__ Wq, ushort* __restrict__ Wq_bf,
                                               const float* __restrict__ Wk, ushort* __restrict__ Wk_bf,
                                               const float* __restrict__ Wv, ushort* __restrict__ Wv_bf,
                                               const float* __restrict__ Wo, ushort* __restrict__ Wo_bf,
                                               const float* __restrict__ ehs, ushort* __restrict__ ehs_bf) {
  const int b0 = 6291456;            // hs quads
  const int b1 = b0 + 589824;        // Wq
  const int b2 = b1 + 786432;        // Wk
  const int b3 = b2 + 786432;        // Wv
  const int b4 = b3 + 589824;        // Wo
  const int total = b4 + 327680;     // ehs (640*2048/4)
  int idx = blockIdx.x * blockDim.x + threadIdx.x;
  int stride = gridDim.x * blockDim.x;
  for (int q = idx; q < total; q += stride) {
    const float* in; ushort* out; int qq;
    bool zero = false;
    if (q < b0)      { in = hs;  out = hs_bf;  qq = q; }
    else if (q < b1) { in = Wq;  out = Wq_bf;  qq = q - b0; }
    else if (q < b2) { in = Wk;  out = Wk_bf;  qq = q - b1; }
    else if (q < b3) { in = Wv;  out = Wv_bf;  qq = q - b2; }
    else if (q < b4) { in = Wo;  out = Wo_bf;  qq = q - b3; }
    else {
      qq = q - b4;
      int r = qq >> 9;               // 512 quads per 2048-col row
      in = ehs; out = ehs_bf;
      zero = (r >= 616);
    }
    ushort4 o;
    if (!zero) {
      float4 f = reinterpret_cast<const float4*>(in)[qq];
      o.x = f2bf(f.x); o.y = f2bf(f.y); o.z = f2bf(f.z); o.w = f2bf(f.w);
    } else {
      o.x = 0; o.y = 0; o.z = 0; o.w = 0;
    }
    reinterpret_cast<ushort4*>(out)[qq] = o;
  }
}

// ---------------- deep-pipelined bf16 MFMA GEMM, 128^2 (round-3 proven) ----------

template <typename OutT>
DEV void gemm_body(const ushort* __restrict__ A, const ushort* __restrict__ B,
                   const float* __restrict__ bias, OutT* __restrict__ C,
                   int M, int N, int K) {
  __shared__ __align__(16) ushort lds[32768];  // 2 bufs x (A 16KB | B 16KB)
  const int tid = threadIdx.x;
  const int lane = tid & 63;
  const int wid = tid >> 6;
  const int wr = wid >> 1, wc = wid & 1;

  // bijective XCD swizzle, m-major decomposition
  const int nwg = gridDim.x * gridDim.y;
  const int lin = blockIdx.y * gridDim.x + blockIdx.x;
  const int q8 = nwg >> 3, r8 = nwg & 7;
  const int xcd = lin & 7, i8 = lin >> 3;
  const int swl = (xcd < r8 ? xcd * (q8 + 1) : r8 * (q8 + 1) + (xcd - r8) * q8) + i8;
  const long m0 = (long)(swl / gridDim.y) * 128;
  const long n0 = (long)(swl % gridDim.y) * 128;

  const int ll = lane & 15, g = lane >> 4;
  const int swz = ll & 7;

  const int srow = wid * 8 + (lane >> 3);
  const int scol = ((lane & 7) ^ (lane >> 3)) * 8;
  const ushort* pa = A + (m0 + srow) * (long)K + scol;
  const ushort* pb = B + (n0 + srow) * (long)K + scol;
  const long qstep = 32 * (long)K;

  f32x4 acc[4][4] = {};

#define STAGE(tt, bsel)                                                                    \
  do {                                                                                     \
    const long kt_ = (long)(tt) * 64;                                                      \
    const int ab_ = (bsel) * 32768 + wid * 1024;                                           \
    _Pragma("unroll") for (int q = 0; q < 4; ++q)                                          \
        __builtin_amdgcn_global_load_lds(                                                  \
            (const __attribute__((address_space(1))) void*)(pa + kt_ + q * qstep),         \
            (__attribute__((address_space(3))) void*)((char*)lds + ab_ + q * 4096),        \
            16, 0, 0);                                                                     \
    _Pragma("unroll") for (int q = 0; q < 4; ++q)                                          \
        __builtin_amdgcn_global_load_lds(                                                  \
            (const __attribute__((address_space(1))) void*)(pb + kt_ + q * qstep),         \
            (__attribute__((address_space(3))) void*)((char*)lds + ab_ + 16384 + q * 4096),\
            16, 0, 0);                                                                     \
  } while (0)

  const int nt = K >> 6;
  STAGE(0, 0);
  STAGE(1, 1);
  asm volatile("s_waitcnt vmcnt(8)" ::: "memory");
  __builtin_amdgcn_s_barrier();

  for (int t = 0; t < nt; ++t) {
    const int buf = t & 1;
    const char* abase = (const char*)lds + buf * 32768;
    const char* bbase = abase + 16384;
    short8 af[4][2], bfr[4][2];
#pragma unroll
    for (int m = 0; m < 4; ++m)
#pragma unroll
      for (int ks = 0; ks < 2; ++ks)
        af[m][ks] = *reinterpret_cast<const short8*>(
            abase + (wr * 64 + m * 16 + ll) * 128 + (((ks * 4 + g) ^ swz) * 16));
#pragma unroll
    for (int n = 0; n < 4; ++n)
#pragma unroll
      for (int ks = 0; ks < 2; ++ks)
        bfr[n][ks] = *reinterpret_cast<const short8*>(
            bbase + (wc * 64 + n * 16 + ll) * 128 + (((ks * 4 + g) ^ swz) * 16));
    asm volatile("s_waitcnt lgkmcnt(0)" ::: "memory");
    __builtin_amdgcn_s_barrier();

    if (t < nt - 2) {
      STAGE(t + 2, buf);
      asm volatile("s_waitcnt vmcnt(8)" ::: "memory");
    } else if (t == nt - 2) {
      asm volatile("s_waitcnt vmcnt(0)" ::: "memory");
    }
    __builtin_amdgcn_sched_barrier(0);
    __builtin_amdgcn_s_setprio(1);
#pragma unroll
    for (int ks = 0; ks < 2; ++ks)
#pragma unroll
      for (int m = 0; m < 4; ++m)
#pragma unroll
        for (int n = 0; n < 4; ++n)
          acc[m][n] =
              __builtin_amdgcn_mfma_f32_16x16x32_bf16(af[m][ks], bfr[n][ks], acc[m][n], 0, 0, 0);
    __builtin_amdgcn_s_setprio(0);
    __builtin_amdgcn_s_barrier();
  }
#undef STAGE

#pragma unroll
  for (int m = 0; m < 4; ++m) {
#pragma unroll
    for (int n = 0; n < 4; ++n) {
      const int row = wr * 64 + m * 16 + g * 4;
      const int col = wc * 64 + n * 16 + ll;
      const float bias_v = bias[n0 + col];
#pragma unroll
      for (int r = 0; r < 4; ++r) {
        float val = acc[m][n][r] + bias_v;
        long off = (m0 + row + r) * (long)N + n0 + col;
        if constexpr (sizeof(OutT) == 2) {
          C[off] = (OutT)f2bf(val);
        } else {
          C[off] = val;
        }
      }
    }
  }
}

template <typename OutT>
__global__ __launch_bounds__(256) void gemm_p(const ushort* __restrict__ A,
                                              const ushort* __restrict__ B,
                                              const float* __restrict__ bias,
                                              OutT* __restrict__ C, int M, int N, int K) {
  gemm_body<OutT>(A, B, bias, C, M, N, K);
}

// K and V projections fused into one launch (blockIdx.z selects)
__global__ __launch_bounds__(256) void gemm_p_kv(const ushort* __restrict__ A,
                                                 const ushort* __restrict__ Bk,
                                                 const float* __restrict__ bk, float* Ck,
                                                 const ushort* __restrict__ Bv,
                                                 const float* __restrict__ bv, float* Cv,
                                                 int M, int N, int K) {
  if (blockIdx.z == 0)
    gemm_body<float>(A, Bk, bk, Ck, M, N, K);
  else
    gemm_body<float>(A, Bv, bv, Cv, M, N, K);
}

// ---------------- 256^2 8-phase GEMM (derived m201-style schedule) ----------------
// 512 thr = 8 waves (wr=w>>2, wc=w&3), per-wave C 128x64. BK=64. LDS 128KB dyn:
// [buf][A 32KB | B 32KB], halves of 128 rows. Per window (4 phases, tile t, buf b):
//   P0: ds_read B(all 8) + A-lo ks0 (12 reads); MFMA (m0-3,ks0)
//   P1: ds_read A-lo ks1 + A-hi (12);           MFMA (m0-3,ks1)
//   P2: MFMA (m4-7,ks0);  P3: MFMA (m4-7,ks1)
// => B(b) free after P0's end-barrier, A(b) free after P1's. Stage 1 half/phase:
//   ph1:A1(t+1->b1) ph2:B0(t+2->b0) ph3:B1 ph4:A0+vmcnt(6) ph5:A1(t+2)
//   ph6:B0(t+3->b1) ph7:B1 ph8:A0+vmcnt(6) next-ph1:A1(t+3)
// Confirm proof: slots read ph1-4 staged <= ph5 (conf. at ph8 vmcnt(6), 3 outst.);
// slots read ph5-8 staged <= ph1 (conf. at ph4 vmcnt(6)). Write-after-read: each
// stage's region fully read >=1 phase-end-barrier earlier (reads pinned by in-phase
// lgkmcnt(0) memory clobber). Prologue 7 stages + vmcnt(6); epilogue vmcnt(0) at
// last ph4. Requires M%256==0, N%256==0, K%128==0, K>=256, grid%8==0.

#define BAR8 __builtin_amdgcn_s_barrier()
#define LGKM0_8 do { asm volatile("s_waitcnt lgkmcnt(0)" ::: "memory"); \
                     __builtin_amdgcn_sched_barrier(0); } while (0)
#define VMC(n_) do { asm volatile("s_waitcnt vmcnt(" #n_ ")" ::: "memory"); \
                     __builtin_amdgcn_sched_barrier(0); } while (0)

template <typename OutT>
__global__ __launch_bounds__(512, 1) void gemm8p(const ushort* __restrict__ A,
                                                 const ushort* __restrict__ B,
                                                 const float* __restrict__ bias,
                                                 OutT* __restrict__ C,
                                                 int M, int N, int K, int nnx) {
  extern __shared__ char dl[];
  const int tid = threadIdx.x;
  const int lane = tid & 63;
  const int w = tid >> 6;
  const int wr = w >> 2, wc = w & 3;
  const int ll = lane & 15, g = lane >> 4;
  const int swz = ll & 7;

  // bijective XCD swizzle (grid % 8 == 0), m-major decomposition
  const int cpx = gridDim.x >> 3;
  const int sw = (blockIdx.x & 7) * cpx + (blockIdx.x >> 3);
  const long m0 = (long)(sw / nnx) * 256;
  const long n0 = (long)(sw % nnx) * 256;

  // staging: srow = tid>>3 (0..63), chunk tid&7, pre-swizzled source col
  const int srow = tid >> 3;
  const int scol = ((tid & 7) ^ (srow & 7)) * 8;
  const ushort* pa = A + (m0 + srow) * (long)K + scol;
  const ushort* pb = B + (n0 + srow) * (long)K + scol;

  // stage one half-tile (128 rows x 64 cols): 2 x global_load_lds per thread
#define STG8(mat, tt, h, bf_)                                                              \
  do {                                                                                     \
    const ushort* s_ = ((mat) ? pb : pa) + (long)((h) * 128) * K + (long)(tt) * 64;        \
    char* d_ = dl + (bf_) * 65536 + (mat) * 32768 + (h) * 16384 + tid * 16;                \
    __builtin_amdgcn_global_load_lds((const __attribute__((address_space(1))) void*)s_,    \
        (__attribute__((address_space(3))) void*)d_, 16, 0, 0);                            \
    __builtin_amdgcn_global_load_lds(                                                      \
        (const __attribute__((address_space(1))) void*)(s_ + 64 * (long)K),                \
        (__attribute__((address_space(3))) void*)(d_ + 8192), 16, 0, 0);                   \
  } while (0)

#define RD_B8(bf_)                                                                         \
  _Pragma("unroll") for (int n = 0; n < 4; ++n)                                            \
  _Pragma("unroll") for (int k2 = 0; k2 < 2; ++k2)                                         \
    bfr[n][k2] = *reinterpret_cast<const short8*>(                                         \
        dl + (bf_) * 65536 + 32768 + (wc * 64 + n * 16 + ll) * 128 +                       \
        (((k2 * 4 + g) ^ swz) * 16));

#define RD_ALO8(bf_, k2)                                                                   \
  _Pragma("unroll") for (int m = 0; m < 4; ++m)                                            \
    aLo[m][k2] = *reinterpret_cast<const short8*>(                                         \
        dl + (bf_) * 65536 + (wr * 128 + m * 16 + ll) * 128 +                              \
        ((((k2) * 4 + g) ^ swz) * 16));

#define RD_AHI8(bf_)                                                                       \
  _Pragma("unroll") for (int m = 0; m < 4; ++m)                                            \
  _Pragma("unroll") for (int k2 = 0; k2 < 2; ++k2)                                         \
    aHi[m][k2] = *reinterpret_cast<const short8*>(                                         \
        dl + (bf_) * 65536 + (wr * 128 + 64 + m * 16 + ll) * 128 +                         \
        (((k2 * 4 + g) ^ swz) * 16));

#define MF8(ab, areg, k2)                                                                  \
  do {                                                                                     \
    __builtin_amdgcn_s_setprio(1);                                                         \
    _Pragma("unroll") for (int m = 0; m < 4; ++m)                                          \
    _Pragma("unroll") for (int n = 0; n < 4; ++n)                                          \
      acc[(ab) + m][n] = __builtin_amdgcn_mfma_f32_16x16x32_bf16(                          \
          areg[m][k2], bfr[n][k2], acc[(ab) + m][n], 0, 0, 0);                             \
    __builtin_amdgcn_s_setprio(0);                                                         \
  } while (0)

  f32x4 acc[8][4] = {};
  short8 aLo[4][2], aHi[4][2], bfr[4][2];

  const int nt = K >> 6;          // even, >= 4
  // prologue: tile0 -> buf0 (B0,B1,A0,A1), tile1 -> buf1 (B0,B1,A0)
  STG8(1, 0, 0, 0); STG8(1, 0, 1, 0); STG8(0, 0, 0, 0); STG8(0, 0, 1, 0);
  STG8(1, 1, 0, 1); STG8(1, 1, 1, 1); STG8(0, 1, 0, 1);
  VMC(6);                         // tile0's 4 stages confirmed (3 outstanding)
  BAR8;

  const int iters = nt / 2 - 1;
  for (int i = 0; i < iters; ++i) {
    const int t = 2 * i;
    // ph1 (W0.P0)
    RD_B8(0); RD_ALO8(0, 0);
    STG8(0, t + 1, 1, 1);         // A1(t+1) -> buf1
    BAR8; LGKM0_8; MF8(0, aLo, 0); BAR8;
    // ph2 (W0.P1)
    RD_ALO8(0, 1); RD_AHI8(0);
    STG8(1, t + 2, 0, 0);         // B0(t+2) -> buf0
    BAR8; LGKM0_8; MF8(0, aLo, 1); BAR8;
    // ph3 (W0.P2)
    STG8(1, t + 2, 1, 0);         // B1(t+2)
    BAR8; MF8(4, aHi, 0); BAR8;
    // ph4 (W0.P3)
    STG8(0, t + 2, 0, 0);         // A0(t+2)
    VMC(6);
    BAR8; MF8(4, aHi, 1); BAR8;
    // ph5 (W1.P0)
    RD_B8(1); RD_ALO8(1, 0);
    STG8(0, t + 2, 1, 0);         // A1(t+2) -> buf0
    BAR8; LGKM0_8; MF8(0, aLo, 0); BAR8;
    // ph6 (W1.P1)
    RD_ALO8(1, 1); RD_AHI8(1);
    STG8(1, t + 3, 0, 1);         // B0(t+3) -> buf1
    BAR8; LGKM0_8; MF8(0, aLo, 1); BAR8;
    // ph7 (W1.P2)
    STG8(1, t + 3, 1, 1);         // B1(t+3)
    BAR8; MF8(4, aHi, 0); BAR8;
    // ph8 (W1.P3)
    STG8(0, t + 3, 0, 1);         // A0(t+3)
    VMC(6);
    BAR8; MF8(4, aHi, 1); BAR8;
  }
  // epilogue: tiles nt-2 (buf0), nt-1 (buf1)
  RD_B8(0); RD_ALO8(0, 0);
  STG8(0, nt - 1, 1, 1);          // A1(nt-1) -> buf1 (last stage)
  BAR8; LGKM0_8; MF8(0, aLo, 0); BAR8;
  RD_ALO8(0, 1); RD_AHI8(0);
  BAR8; LGKM0_8; MF8(0, aLo, 1); BAR8;
  BAR8; MF8(4, aHi, 0); BAR8;
  VMC(0);                         // all stages landed (incl. A1(nt-1))
  BAR8; MF8(4, aHi, 1); BAR8;
  RD_B8(1); RD_ALO8(1, 0);
  BAR8; LGKM0_8; MF8(0, aLo, 0); BAR8;
  RD_ALO8(1, 1); RD_AHI8(1);
  BAR8; LGKM0_8; MF8(0, aLo, 1); BAR8;
  MF8(4, aHi, 0);
  MF8(4, aHi, 1);

#undef STG8
#undef RD_B8
#undef RD_ALO8
#undef RD_AHI8
#undef MF8

  // epilogue C-write: row = wr*128 + m*16 + g*4 + r, col = wc*64 + n*16 + ll
#pragma unroll
  for (int m = 0; m < 8; ++m) {
#pragma unroll
    for (int n = 0; n < 4; ++n) {
      const int row = wr * 128 + m * 16 + g * 4;
      const int col = wc * 64 + n * 16 + ll;
      const float bias_v = bias[n0 + col];
#pragma unroll
      for (int r = 0; r < 4; ++r) {
        float val = acc[m][n][r] + bias_v;
        long off = (m0 + row + r) * (long)N + n0 + col;
        if constexpr (sizeof(OutT) == 2) {
          C[off] = (OutT)f2bf(val);
        } else {
          C[off] = val;
        }
      }
    }
  }
}

// ---------------- prep: build attn images once ----------------

__global__ __launch_bounds__(256) void prep_kv(const float* __restrict__ k_f,
                                               const float* __restrict__ v_f,
                                               const float* __restrict__ bk,
                                               const float* __restrict__ bv,
                                               ushort* __restrict__ kimg,
                                               ushort* __restrict__ vimg) {
  __shared__ _Float16 vl[80][68];
  const int c = blockIdx.x, h = blockIdx.y, bb = blockIdx.z;
  const int tid = threadIdx.x;
  const long ibase = ((long)(bb * 24 + h)) * 20480 + c * 5120;

  for (int rr = tid; rr < 640; rr += 256) {
    int j = rr >> 3, t = rr & 7;
    short8 v = {};
    const float* src = nullptr;
    if (j < 77)
      src = k_f + ((long)((c * 2 + bb) * 77 + j)) * 1536 + h * 64 + t * 8;
    else if (j == 77)
      src = bk + h * 64 + t * 8;
    if (src) {
      float4 f0 = reinterpret_cast<const float4*>(src)[0];
      float4 f1 = reinterpret_cast<const float4*>(src)[1];
      v[0] = f2bf(f0.x); v[1] = f2bf(f0.y); v[2] = f2bf(f0.z); v[3] = f2bf(f0.w);
      v[4] = f2bf(f1.x); v[5] = f2bf(f1.y); v[6] = f2bf(f1.z); v[7] = f2bf(f1.w);
    }
    *reinterpret_cast<short8*>(kimg + ibase + j * 64 + (t ^ (j & 7)) * 8) = v;
  }
  for (int rr = tid; rr < 640; rr += 256) {
    int j = rr >> 3, t = rr & 7;
    half4 lo = {}, hi = {};
    const float* src = nullptr;
    if (j < 77)
      src = v_f + ((long)((c * 2 + bb) * 77 + j)) * 1536 + h * 64 + t * 8;
    else if (j == 77)
      src = bv + h * 64 + t * 8;
    if (src) {
      float4 f0 = reinterpret_cast<const float4*>(src)[0];
      float4 f1 = reinterpret_cast<const float4*>(src)[1];
      lo[0] = (_Float16)f0.x; lo[1] = (_Float16)f0.y; lo[2] = (_Float16)f0.z; lo[3] = (_Float16)f0.w;
      hi[0] = (_Float16)f1.x; hi[1] = (_Float16)f1.y; hi[2] = (_Float16)f1.z; hi[3] = (_Float16)f1.w;
    }
    *reinterpret_cast<half4*>(&vl[j][t * 8]) = lo;
    *reinterpret_cast<half4*>(&vl[j][t * 8 + 4]) = hi;
  }
  __syncthreads();
  const int d = tid & 63, jg = tid >> 6;
  ushort* vrow = vimg + ibase + d * 80;
  const int x = (d >> 2) & 3;
#pragma unroll
  for (int b = 0; b < 5; ++b) {
    int jb = jg * 5 + b;
    half4 hv;
#pragma unroll
    for (int e = 0; e < 4; ++e) hv[e] = vl[jb * 4 + e][d];
    *reinterpret_cast<half4*>(vrow + ((jb ^ x) << 2)) = hv;
  }
}

// ---------------- MFMA component-softmax attention (v4) ----------------

__global__ __launch_bounds__(256) void attn_v4(const ushort* __restrict__ qg,
                                               const ushort* __restrict__ kimg,
                                               const ushort* __restrict__ vimg,
                                               ushort* __restrict__ ao) {
  __shared__ __align__(16) ushort vt[20480];   // 40 KB (f16 bits)
  const int tid = threadIdx.x;
  const int lane = tid & 63;
  const int w = tid >> 6;
  const int h = blockIdx.y, bb = blockIdx.z;
  const int i0 = blockIdx.x * 64;
  const long ib = ((long)(bb * 24 + h)) * 20480;

#pragma unroll
  for (int p = 0; p < 10; ++p) {
    int is = p * 4 + w;
    __builtin_amdgcn_global_load_lds(
        (const __attribute__((address_space(1))) void*)(vimg + ib + is * 512 + lane * 8),
        (__attribute__((address_space(3))) void*)((char*)vt + is * 1024), 16, 0, 0);
  }

  const int ll = lane & 15, g = lane >> 4;

  f32x4 s[4][5];
#pragma unroll
  for (int c = 0; c < 4; ++c)
#pragma unroll
    for (int m = 0; m < 5; ++m) s[c][m] = (f32x4){0.f, 0.f, 0.f, 0.f};

#pragma unroll
  for (int c = 0; c < 4; ++c) {
    const ushort* qbase =
        qg + ((long)((c * 2 + bb) * 2048 + i0 + w * 16 + ll)) * 1536 + h * 64 + g * 8;
    short8 qf0 = *reinterpret_cast<const short8*>(qbase);
    short8 qf1 = *reinterpret_cast<const short8*>(qbase + 32);
    const ushort* kbase = kimg + ib + c * 5120;
#pragma unroll
    for (int m = 0; m < 5; ++m) {
      const ushort* rb = kbase + (m * 16 + ll) * 64;
      short8 a0 = *reinterpret_cast<const short8*>(rb + (g ^ (ll & 7)) * 8);
      short8 a1 = *reinterpret_cast<const short8*>(rb + ((4 + g) ^ (ll & 7)) * 8);
      s[c][m] = __builtin_amdgcn_mfma_f32_16x16x32_bf16(a0, qf0, s[c][m], 0, 0, 0);
      s[c][m] = __builtin_amdgcn_mfma_f32_16x16x32_bf16(a1, qf1, s[c][m], 0, 0, 0);
    }
  }

  const float scale = 0.125f;
  float wsum0 = 0.f, wsum1 = 0.f, wsum2 = 0.f, wsum3 = 0.f;
#pragma unroll
  for (int m = 0; m < 5; ++m) {
#pragma unroll
    for (int e = 0; e < 4; ++e) {
      float x0 = s[0][m][e] * scale, x1 = s[1][m][e] * scale;
      float x2 = s[2][m][e] * scale, x3 = s[3][m][e] * scale;
      float mx = fmaxf(fmaxf(x0, x1), fmaxf(x2, x3));
      float e0 = __expf(x0 - mx), e1 = __expf(x1 - mx);
      float e2 = __expf(x2 - mx), e3 = __expf(x3 - mx);
      float inv = __fdividef(1.f, e0 + e1 + e2 + e3);
      float w0 = e0 * inv, w1 = e1 * inv, w2 = e2 * inv, w3 = e3 * inv;
      int jj = m * 16 + g * 4 + e;
      float msk = (jj < 77) ? 1.f : 0.f;
      wsum0 += w0 * msk; wsum1 += w1 * msk; wsum2 += w2 * msk; wsum3 += w3 * msk;
      s[0][m][e] = w0; s[1][m][e] = w1; s[2][m][e] = w2; s[3][m][e] = w3;
    }
  }
  wsum0 += __shfl_xor(wsum0, 16); wsum0 += __shfl_xor(wsum0, 32);
  wsum1 += __shfl_xor(wsum1, 16); wsum1 += __shfl_xor(wsum1, 32);
  wsum2 += __shfl_xor(wsum2, 16); wsum2 += __shfl_xor(wsum2, 32);
  wsum3 += __shfl_xor(wsum3, 16); wsum3 += __shfl_xor(wsum3, 32);

  const bool g3 = (g == 3);
  {
    float wsum[4] = {wsum0, wsum1, wsum2, wsum3};
#pragma unroll
    for (int c = 0; c < 4; ++c) {
      float w77 = s[c][4][1];
      float pwv = w77 * (4.0f / 77.0f) * (77.0f - wsum[c]);
      s[c][4][1] = g3 ? pwv : w77;
      s[c][4][2] = g3 ? 0.f : s[c][4][2];
      s[c][4][3] = g3 ? 0.f : s[c][4][3];
    }
  }

  half4 wf[4][5];
#pragma unroll
  for (int c = 0; c < 4; ++c)
#pragma unroll
    for (int m = 0; m < 5; ++m) {
      half4 hv;
      hv[0] = (_Float16)s[c][m][0];
      hv[1] = (_Float16)s[c][m][1];
      hv[2] = (_Float16)s[c][m][2];
      hv[3] = (_Float16)s[c][m][3];
      wf[c][m] = hv;
    }

  __syncthreads();  // V^T staged (drains vmcnt) before PV reads it

  f32x4 o[4][4];
#pragma unroll
  for (int c = 0; c < 4; ++c)
#pragma unroll
    for (int n = 0; n < 4; ++n) o[c][n] = (f32x4){0.f, 0.f, 0.f, 0.f};

#pragma unroll
  for (int c = 0; c < 4; ++c)
#pragma unroll
    for (int m = 0; m < 5; ++m)
#pragma unroll
      for (int n = 0; n < 4; ++n) {
        const int dd = n * 16 + ll;
        const int jb = (m * 4 + g) ^ ((dd >> 2) & 3);
        half4 vf = *reinterpret_cast<const half4*>(
            reinterpret_cast<const _Float16*>(vt) + c * 5120 + dd * 80 + (jb << 2));
        o[c][n] = __builtin_amdgcn_mfma_f32_16x16x16f16(wf[c][m], vf, o[c][n], 0, 0, 0);
      }

#pragma unroll
  for (int c = 0; c < 4; ++c)
#pragma unroll
    for (int n = 0; n < 4; ++n)
#pragma unroll
      for (int r = 0; r < 4; ++r) {
        long row = (long)((c * 2 + bb) * 2048 + i0 + w * 16 + g * 4 + r);
        ao[row * 1536 + h * 64 + n * 16 + ll] = f2bf(o[c][n][r]);
      }
}

// ---------------- launcher ----------------

extern "C" void kernel_launch(void* const* d_in, const int* in_sizes, int n_in,
                              void* d_out, int out_size, void* d_ws, size_t ws_size,
                              hipStream_t stream) {
  (void)in_sizes; (void)n_in; (void)out_size; (void)ws_size;
  const float* hs  = (const float*)d_in[0];
  const float* ehs = (const float*)d_in[1];
  const float* Wq  = (const float*)d_in[2];
  const float* bq  = (const float*)d_in[3];
  const float* Wk  = (const float*)d_in[4];
  const float* bk  = (const float*)d_in[5];
  const float* Wv  = (const float*)d_in[6];
  const float* bv  = (const float*)d_in[7];
  const float* Wo  = (const float*)d_in[8];
  const float* bo  = (const float*)d_in[9];
  float* out = (float*)d_out;

  char* ws = (char*)d_ws;
  size_t off = 0;
  auto alloc = [&](size_t bytes) {
    char* p = ws + off;
    off += (bytes + 255) & ~(size_t)255;
    return p;
  };
  ushort* hs_bf  = (ushort*)alloc(16384UL * 1536 * 2);
  ushort* ehs_bf = (ushort*)alloc(640UL * 2048 * 2);
  ushort* Wq_bf  = (ushort*)alloc(1536UL * 1536 * 2);
  ushort* Wk_bf  = (ushort*)alloc(1536UL * 2048 * 2);
  ushort* Wv_bf  = (ushort*)alloc(1536UL * 2048 * 2);
  ushort* Wo_bf  = (ushort*)alloc(1536UL * 1536 * 2);
  ushort* q_bf   = (ushort*)alloc(16384UL * 1536 * 2);
  float*  k_f    = (float*)alloc(640UL * 1536 * 4);
  float*  v_f    = (float*)alloc(640UL * 1536 * 4);
  ushort* ao_bf  = (ushort*)alloc(16384UL * 1536 * 2);
  ushort* kimg   = (ushort*)alloc(48UL * 20480 * 2);
  ushort* vimg   = (ushort*)alloc(48UL * 20480 * 2);

  // allow 128 KB dynamic LDS (deterministic, called every launch)
  hipFuncSetAttribute(reinterpret_cast<const void*>(&gemm8p<ushort>),
                      hipFuncAttributeMaxDynamicSharedMemorySize, 131072);

  dim3 b256(256);
  cvt_all<<<4096, b256, 0, stream>>>(hs, hs_bf, Wq, Wq_bf, Wk, Wk_bf, Wv, Wv_bf,
                                     Wo, Wo_bf, ehs, ehs_bf);

  // K,V projections fused (M padded to 640; rows 616..639 bias-only, unused)
  gemm_p_kv<<<dim3(5, 12, 2), b256, 0, stream>>>(ehs_bf, Wk_bf, bk, k_f, Wv_bf, bv, v_f,
                                                 640, 1536, 2048);
  // build attn images
  prep_kv<<<dim3(4, 24, 2), b256, 0, stream>>>(k_f, v_f, bk, bv, kimg, vimg);
  // Q projection: 8-phase 256^2 kernel (A/B vs gemm_p on the O projection)
  gemm8p<ushort><<<384, 512, 131072, stream>>>(hs_bf, Wq_bf, bq, q_bf, 16384, 1536, 1536, 6);
  // MFMA component-softmax attention
  attn_v4<<<dim3(32, 24, 2), b256, 0, stream>>>(q_bf, kimg, vimg, ao_bf);
  // output projection -> d_out (f32): proven 128^2 kernel
  gemm_p<float><<<dim3(128, 12), b256, 0, stream>>>(ao_bf, Wo_bf, bo, out, 16384, 1536, 1536);
}

// Round 14
// 266.402 us; speedup vs baseline: 1.1498x; 1.1498x over previous
//
#include <hip/hip_runtime.h>
#include <hip/hip_bf16.h>

// Shapes (hardcoded from reference): C=4, B=2, BC=8, HEADS=24, DH=64, D=1536,
// CROSS=2048, S=2048, E=PAD=77. Output f32 [8,2048,1536].
// FINAL (r14 = r12 config, session best 265.1 us):
//   cvt_all -> gemm_p_kv -> prep_kv -> gemm_p(Q) -> attn_v4 -> gemm_p(O)

typedef __attribute__((ext_vector_type(8))) short short8;
typedef __attribute__((ext_vector_type(4))) float f32x4;
typedef __attribute__((ext_vector_type(4))) _Float16 half4;

#define DEV __device__ __forceinline__

DEV ushort f2bf(float x) {
  __hip_bfloat16 h = __float2bfloat16(x);
  return *reinterpret_cast<ushort*>(&h);
}

// ---------------- merged conversion kernel ----------------

__global__ __launch_bounds__(256) void cvt_all(const float* __restrict__ hs, ushort* __restrict__ hs_bf,
                                               const float* __restrict__ Wq, ushort* __restrict__ Wq_bf,
                                               const float* __restrict__ Wk, ushort* __restrict__ Wk_bf,
                                               const float* __restrict__ Wv, ushort* __restrict__ Wv_bf,
                                               const float* __restrict__ Wo, ushort* __restrict__ Wo_bf,
                                               const float* __restrict__ ehs, ushort* __restrict__ ehs_bf) {
  const int b0 = 6291456;            // hs quads
  const int b1 = b0 + 589824;        // Wq
  const int b2 = b1 + 786432;        // Wk
  const int b3 = b2 + 786432;        // Wv
  const int b4 = b3 + 589824;        // Wo
  const int total = b4 + 327680;     // ehs (640*2048/4)
  int idx = blockIdx.x * blockDim.x + threadIdx.x;
  int stride = gridDim.x * blockDim.x;
  for (int q = idx; q < total; q += stride) {
    const float* in; ushort* out; int qq;
    bool zero = false;
    if (q < b0)      { in = hs;  out = hs_bf;  qq = q; }
    else if (q < b1) { in = Wq;  out = Wq_bf;  qq = q - b0; }
    else if (q < b2) { in = Wk;  out = Wk_bf;  qq = q - b1; }
    else if (q < b3) { in = Wv;  out = Wv_bf;  qq = q - b2; }
    else if (q < b4) { in = Wo;  out = Wo_bf;  qq = q - b3; }
    else {
      qq = q - b4;
      int r = qq >> 9;               // 512 quads per 2048-col row
      in = ehs; out = ehs_bf;
      zero = (r >= 616);
    }
    ushort4 o;
    if (!zero) {
      float4 f = reinterpret_cast<const float4*>(in)[qq];
      o.x = f2bf(f.x); o.y = f2bf(f.y); o.z = f2bf(f.z); o.w = f2bf(f.w);
    } else {
      o.x = 0; o.y = 0; o.z = 0; o.w = 0;
    }
    reinterpret_cast<ushort4*>(out)[qq] = o;
  }
}

// ---------------- deep-pipelined bf16 MFMA GEMM, 128^2 (round-3 proven) ----------
// C[m][n] = sum_k A[m][k]*B[n][k] + bias[n].  128x128 tile, BK=64, 4 waves (2x2).
// Double-buffered LDS (64 KB -> 2 blocks/CU). Raw s_barrier + counted vmcnt.
// T2 swizzle on LDS; bijective XCD block swizzle (m204), m-major decomposition.
// A/B-validated best vs: B-from-L2 (r4), 256^2 coarse (r6), fused-cvt (r8),
// BK=32 256^2 (r9), BK=32 4-ring (r10), derived 8-phase (r13) -- all regressed.

template <typename OutT>
DEV void gemm_body(const ushort* __restrict__ A, const ushort* __restrict__ B,
                   const float* __restrict__ bias, OutT* __restrict__ C,
                   int M, int N, int K) {
  __shared__ __align__(16) ushort lds[32768];  // 2 bufs x (A 16KB | B 16KB)
  const int tid = threadIdx.x;
  const int lane = tid & 63;
  const int wid = tid >> 6;
  const int wr = wid >> 1, wc = wid & 1;

  // bijective XCD swizzle, m-major decomposition
  const int nwg = gridDim.x * gridDim.y;
  const int lin = blockIdx.y * gridDim.x + blockIdx.x;
  const int q8 = nwg >> 3, r8 = nwg & 7;
  const int xcd = lin & 7, i8 = lin >> 3;
  const int swl = (xcd < r8 ? xcd * (q8 + 1) : r8 * (q8 + 1) + (xcd - r8) * q8) + i8;
  const long m0 = (long)(swl / gridDim.y) * 128;
  const long n0 = (long)(swl % gridDim.y) * 128;

  const int ll = lane & 15, g = lane >> 4;
  const int swz = ll & 7;

  const int srow = wid * 8 + (lane >> 3);
  const int scol = ((lane & 7) ^ (lane >> 3)) * 8;
  const ushort* pa = A + (m0 + srow) * (long)K + scol;
  const ushort* pb = B + (n0 + srow) * (long)K + scol;
  const long qstep = 32 * (long)K;

  f32x4 acc[4][4] = {};

#define STAGE(tt, bsel)                                                                    \
  do {                                                                                     \
    const long kt_ = (long)(tt) * 64;                                                      \
    const int ab_ = (bsel) * 32768 + wid * 1024;                                           \
    _Pragma("unroll") for (int q = 0; q < 4; ++q)                                          \
        __builtin_amdgcn_global_load_lds(                                                  \
            (const __attribute__((address_space(1))) void*)(pa + kt_ + q * qstep),         \
            (__attribute__((address_space(3))) void*)((char*)lds + ab_ + q * 4096),        \
            16, 0, 0);                                                                     \
    _Pragma("unroll") for (int q = 0; q < 4; ++q)                                          \
        __builtin_amdgcn_global_load_lds(                                                  \
            (const __attribute__((address_space(1))) void*)(pb + kt_ + q * qstep),         \
            (__attribute__((address_space(3))) void*)((char*)lds + ab_ + 16384 + q * 4096),\
            16, 0, 0);                                                                     \
  } while (0)

  const int nt = K >> 6;
  STAGE(0, 0);
  STAGE(1, 1);
  asm volatile("s_waitcnt vmcnt(8)" ::: "memory");
  __builtin_amdgcn_s_barrier();

  for (int t = 0; t < nt; ++t) {
    const int buf = t & 1;
    const char* abase = (const char*)lds + buf * 32768;
    const char* bbase = abase + 16384;
    short8 af[4][2], bfr[4][2];
#pragma unroll
    for (int m = 0; m < 4; ++m)
#pragma unroll
      for (int ks = 0; ks < 2; ++ks)
        af[m][ks] = *reinterpret_cast<const short8*>(
            abase + (wr * 64 + m * 16 + ll) * 128 + (((ks * 4 + g) ^ swz) * 16));
#pragma unroll
    for (int n = 0; n < 4; ++n)
#pragma unroll
      for (int ks = 0; ks < 2; ++ks)
        bfr[n][ks] = *reinterpret_cast<const short8*>(
            bbase + (wc * 64 + n * 16 + ll) * 128 + (((ks * 4 + g) ^ swz) * 16));
    asm volatile("s_waitcnt lgkmcnt(0)" ::: "memory");
    __builtin_amdgcn_s_barrier();

    if (t < nt - 2) {
      STAGE(t + 2, buf);
      asm volatile("s_waitcnt vmcnt(8)" ::: "memory");
    } else if (t == nt - 2) {
      asm volatile("s_waitcnt vmcnt(0)" ::: "memory");
    }
    __builtin_amdgcn_sched_barrier(0);
    __builtin_amdgcn_s_setprio(1);
#pragma unroll
    for (int ks = 0; ks < 2; ++ks)
#pragma unroll
      for (int m = 0; m < 4; ++m)
#pragma unroll
        for (int n = 0; n < 4; ++n)
          acc[m][n] =
              __builtin_amdgcn_mfma_f32_16x16x32_bf16(af[m][ks], bfr[n][ks], acc[m][n], 0, 0, 0);
    __builtin_amdgcn_s_setprio(0);
    __builtin_amdgcn_s_barrier();
  }
#undef STAGE

#pragma unroll
  for (int m = 0; m < 4; ++m) {
#pragma unroll
    for (int n = 0; n < 4; ++n) {
      const int row = wr * 64 + m * 16 + g * 4;
      const int col = wc * 64 + n * 16 + ll;
      const float bias_v = bias[n0 + col];
#pragma unroll
      for (int r = 0; r < 4; ++r) {
        float val = acc[m][n][r] + bias_v;
        long off = (m0 + row + r) * (long)N + n0 + col;
        if constexpr (sizeof(OutT) == 2) {
          C[off] = (OutT)f2bf(val);
        } else {
          C[off] = val;
        }
      }
    }
  }
}

template <typename OutT>
__global__ __launch_bounds__(256) void gemm_p(const ushort* __restrict__ A,
                                              const ushort* __restrict__ B,
                                              const float* __restrict__ bias,
                                              OutT* __restrict__ C, int M, int N, int K) {
  gemm_body<OutT>(A, B, bias, C, M, N, K);
}

// K and V projections fused into one launch (blockIdx.z selects)
__global__ __launch_bounds__(256) void gemm_p_kv(const ushort* __restrict__ A,
                                                 const ushort* __restrict__ Bk,
                                                 const float* __restrict__ bk, float* Ck,
                                                 const ushort* __restrict__ Bv,
                                                 const float* __restrict__ bv, float* Cv,
                                                 int M, int N, int K) {
  if (blockIdx.z == 0)
    gemm_body<float>(A, Bk, bk, Ck, M, N, K);
  else
    gemm_body<float>(A, Bv, bv, Cv, M, N, K);
}

// ---------------- prep: build attn images once ----------------
// Per (bb,h): kimg = ushort[4][80][64] bf16, row j chunk-swizzled (t ^ (j&7));
//             vimg = f16[4][64][80] V^T with jb-block swizzle (jb ^ ((d>>2)&3)).

__global__ __launch_bounds__(256) void prep_kv(const float* __restrict__ k_f,
                                               const float* __restrict__ v_f,
                                               const float* __restrict__ bk,
                                               const float* __restrict__ bv,
                                               ushort* __restrict__ kimg,
                                               ushort* __restrict__ vimg) {
  __shared__ _Float16 vl[80][68];
  const int c = blockIdx.x, h = blockIdx.y, bb = blockIdx.z;
  const int tid = threadIdx.x;
  const long ibase = ((long)(bb * 24 + h)) * 20480 + c * 5120;

  for (int rr = tid; rr < 640; rr += 256) {
    int j = rr >> 3, t = rr & 7;
    short8 v = {};
    const float* src = nullptr;
    if (j < 77)
      src = k_f + ((long)((c * 2 + bb) * 77 + j)) * 1536 + h * 64 + t * 8;
    else if (j == 77)
      src = bk + h * 64 + t * 8;
    if (src) {
      float4 f0 = reinterpret_cast<const float4*>(src)[0];
      float4 f1 = reinterpret_cast<const float4*>(src)[1];
      v[0] = f2bf(f0.x); v[1] = f2bf(f0.y); v[2] = f2bf(f0.z); v[3] = f2bf(f0.w);
      v[4] = f2bf(f1.x); v[5] = f2bf(f1.y); v[6] = f2bf(f1.z); v[7] = f2bf(f1.w);
    }
    *reinterpret_cast<short8*>(kimg + ibase + j * 64 + (t ^ (j & 7)) * 8) = v;
  }
  for (int rr = tid; rr < 640; rr += 256) {
    int j = rr >> 3, t = rr & 7;
    half4 lo = {}, hi = {};
    const float* src = nullptr;
    if (j < 77)
      src = v_f + ((long)((c * 2 + bb) * 77 + j)) * 1536 + h * 64 + t * 8;
    else if (j == 77)
      src = bv + h * 64 + t * 8;
    if (src) {
      float4 f0 = reinterpret_cast<const float4*>(src)[0];
      float4 f1 = reinterpret_cast<const float4*>(src)[1];
      lo[0] = (_Float16)f0.x; lo[1] = (_Float16)f0.y; lo[2] = (_Float16)f0.z; lo[3] = (_Float16)f0.w;
      hi[0] = (_Float16)f1.x; hi[1] = (_Float16)f1.y; hi[2] = (_Float16)f1.z; hi[3] = (_Float16)f1.w;
    }
    *reinterpret_cast<half4*>(&vl[j][t * 8]) = lo;
    *reinterpret_cast<half4*>(&vl[j][t * 8 + 4]) = hi;
  }
  __syncthreads();
  const int d = tid & 63, jg = tid >> 6;
  ushort* vrow = vimg + ibase + d * 80;
  const int x = (d >> 2) & 3;
#pragma unroll
  for (int b = 0; b < 5; ++b) {
    int jb = jg * 5 + b;
    half4 hv;
#pragma unroll
    for (int e = 0; e < 4; ++e) hv[e] = vl[jb * 4 + e][d];
    *reinterpret_cast<half4*>(vrow + ((jb ^ x) << 2)) = hv;
  }
}

// ---------------- MFMA component-softmax attention (v4) ----------------
// grid (32 i-tiles, 24 heads, 2 bb), block 256 = 4 waves.
// V^T staged async into LDS (40 KB -> 3-4 blocks/CU); K-frags read DIRECTLY
// from L2-resident kimg (3.84 MB). Barrier only between QK/softmax and PV.

__global__ __launch_bounds__(256) void attn_v4(const ushort* __restrict__ qg,
                                               const ushort* __restrict__ kimg,
                                               const ushort* __restrict__ vimg,
                                               ushort* __restrict__ ao) {
  __shared__ __align__(16) ushort vt[20480];   // 40 KB (f16 bits)
  const int tid = threadIdx.x;
  const int lane = tid & 63;
  const int w = tid >> 6;
  const int h = blockIdx.y, bb = blockIdx.z;
  const int i0 = blockIdx.x * 64;
  const long ib = ((long)(bb * 24 + h)) * 20480;

#pragma unroll
  for (int p = 0; p < 10; ++p) {
    int is = p * 4 + w;
    __builtin_amdgcn_global_load_lds(
        (const __attribute__((address_space(1))) void*)(vimg + ib + is * 512 + lane * 8),
        (__attribute__((address_space(3))) void*)((char*)vt + is * 1024), 16, 0, 0);
  }

  const int ll = lane & 15, g = lane >> 4;

  f32x4 s[4][5];
#pragma unroll
  for (int c = 0; c < 4; ++c)
#pragma unroll
    for (int m = 0; m < 5; ++m) s[c][m] = (f32x4){0.f, 0.f, 0.f, 0.f};

#pragma unroll
  for (int c = 0; c < 4; ++c) {
    const ushort* qbase =
        qg + ((long)((c * 2 + bb) * 2048 + i0 + w * 16 + ll)) * 1536 + h * 64 + g * 8;
    short8 qf0 = *reinterpret_cast<const short8*>(qbase);
    short8 qf1 = *reinterpret_cast<const short8*>(qbase + 32);
    const ushort* kbase = kimg + ib + c * 5120;
#pragma unroll
    for (int m = 0; m < 5; ++m) {
      const ushort* rb = kbase + (m * 16 + ll) * 64;
      short8 a0 = *reinterpret_cast<const short8*>(rb + (g ^ (ll & 7)) * 8);
      short8 a1 = *reinterpret_cast<const short8*>(rb + ((4 + g) ^ (ll & 7)) * 8);
      s[c][m] = __builtin_amdgcn_mfma_f32_16x16x32_bf16(a0, qf0, s[c][m], 0, 0, 0);
      s[c][m] = __builtin_amdgcn_mfma_f32_16x16x32_bf16(a1, qf1, s[c][m], 0, 0, 0);
    }
  }

  const float scale = 0.125f;
  float wsum0 = 0.f, wsum1 = 0.f, wsum2 = 0.f, wsum3 = 0.f;
#pragma unroll
  for (int m = 0; m < 5; ++m) {
#pragma unroll
    for (int e = 0; e < 4; ++e) {
      float x0 = s[0][m][e] * scale, x1 = s[1][m][e] * scale;
      float x2 = s[2][m][e] * scale, x3 = s[3][m][e] * scale;
      float mx = fmaxf(fmaxf(x0, x1), fmaxf(x2, x3));
      float e0 = __expf(x0 - mx), e1 = __expf(x1 - mx);
      float e2 = __expf(x2 - mx), e3 = __expf(x3 - mx);
      float inv = __fdividef(1.f, e0 + e1 + e2 + e3);
      float w0 = e0 * inv, w1 = e1 * inv, w2 = e2 * inv, w3 = e3 * inv;
      int jj = m * 16 + g * 4 + e;
      float msk = (jj < 77) ? 1.f : 0.f;
      wsum0 += w0 * msk; wsum1 += w1 * msk; wsum2 += w2 * msk; wsum3 += w3 * msk;
      s[0][m][e] = w0; s[1][m][e] = w1; s[2][m][e] = w2; s[3][m][e] = w3;
    }
  }
  wsum0 += __shfl_xor(wsum0, 16); wsum0 += __shfl_xor(wsum0, 32);
  wsum1 += __shfl_xor(wsum1, 16); wsum1 += __shfl_xor(wsum1, 32);
  wsum2 += __shfl_xor(wsum2, 16); wsum2 += __shfl_xor(wsum2, 32);
  wsum3 += __shfl_xor(wsum3, 16); wsum3 += __shfl_xor(wsum3, 32);

  const bool g3 = (g == 3);
  {
    float wsum[4] = {wsum0, wsum1, wsum2, wsum3};
#pragma unroll
    for (int c = 0; c < 4; ++c) {
      float w77 = s[c][4][1];
      float pwv = w77 * (4.0f / 77.0f) * (77.0f - wsum[c]);
      s[c][4][1] = g3 ? pwv : w77;
      s[c][4][2] = g3 ? 0.f : s[c][4][2];
      s[c][4][3] = g3 ? 0.f : s[c][4][3];
    }
  }

  half4 wf[4][5];
#pragma unroll
  for (int c = 0; c < 4; ++c)
#pragma unroll
    for (int m = 0; m < 5; ++m) {
      half4 hv;
      hv[0] = (_Float16)s[c][m][0];
      hv[1] = (_Float16)s[c][m][1];
      hv[2] = (_Float16)s[c][m][2];
      hv[3] = (_Float16)s[c][m][3];
      wf[c][m] = hv;
    }

  __syncthreads();  // V^T staged (drains vmcnt) before PV reads it

  f32x4 o[4][4];
#pragma unroll
  for (int c = 0; c < 4; ++c)
#pragma unroll
    for (int n = 0; n < 4; ++n) o[c][n] = (f32x4){0.f, 0.f, 0.f, 0.f};

#pragma unroll
  for (int c = 0; c < 4; ++c)
#pragma unroll
    for (int m = 0; m < 5; ++m)
#pragma unroll
      for (int n = 0; n < 4; ++n) {
        const int dd = n * 16 + ll;
        const int jb = (m * 4 + g) ^ ((dd >> 2) & 3);
        half4 vf = *reinterpret_cast<const half4*>(
            reinterpret_cast<const _Float16*>(vt) + c * 5120 + dd * 80 + (jb << 2));
        o[c][n] = __builtin_amdgcn_mfma_f32_16x16x16f16(wf[c][m], vf, o[c][n], 0, 0, 0);
      }

#pragma unroll
  for (int c = 0; c < 4; ++c)
#pragma unroll
    for (int n = 0; n < 4; ++n)
#pragma unroll
      for (int r = 0; r < 4; ++r) {
        long row = (long)((c * 2 + bb) * 2048 + i0 + w * 16 + g * 4 + r);
        ao[row * 1536 + h * 64 + n * 16 + ll] = f2bf(o[c][n][r]);
      }
}

// ---------------- launcher ----------------

extern "C" void kernel_launch(void* const* d_in, const int* in_sizes, int n_in,
                              void* d_out, int out_size, void* d_ws, size_t ws_size,
                              hipStream_t stream) {
  (void)in_sizes; (void)n_in; (void)out_size; (void)ws_size;
  const float* hs  = (const float*)d_in[0];
  const float* ehs = (const float*)d_in[1];
  const float* Wq  = (const float*)d_in[2];
  const float* bq  = (const float*)d_in[3];
  const float* Wk  = (const float*)d_in[4];
  const float* bk  = (const float*)d_in[5];
  const float* Wv  = (const float*)d_in[6];
  const float* bv  = (const float*)d_in[7];
  const float* Wo  = (const float*)d_in[8];
  const float* bo  = (const float*)d_in[9];
  float* out = (float*)d_out;

  char* ws = (char*)d_ws;
  size_t off = 0;
  auto alloc = [&](size_t bytes) {
    char* p = ws + off;
    off += (bytes + 255) & ~(size_t)255;
    return p;
  };
  ushort* hs_bf  = (ushort*)alloc(16384UL * 1536 * 2);
  ushort* ehs_bf = (ushort*)alloc(640UL * 2048 * 2);
  ushort* Wq_bf  = (ushort*)alloc(1536UL * 1536 * 2);
  ushort* Wk_bf  = (ushort*)alloc(1536UL * 2048 * 2);
  ushort* Wv_bf  = (ushort*)alloc(1536UL * 2048 * 2);
  ushort* Wo_bf  = (ushort*)alloc(1536UL * 1536 * 2);
  ushort* q_bf   = (ushort*)alloc(16384UL * 1536 * 2);
  float*  k_f    = (float*)alloc(640UL * 1536 * 4);
  float*  v_f    = (float*)alloc(640UL * 1536 * 4);
  ushort* ao_bf  = (ushort*)alloc(16384UL * 1536 * 2);
  ushort* kimg   = (ushort*)alloc(48UL * 20480 * 2);
  ushort* vimg   = (ushort*)alloc(48UL * 20480 * 2);

  dim3 b256(256);
  cvt_all<<<4096, b256, 0, stream>>>(hs, hs_bf, Wq, Wq_bf, Wk, Wk_bf, Wv, Wv_bf,
                                     Wo, Wo_bf, ehs, ehs_bf);

  // K,V projections fused (M padded to 640; rows 616..639 bias-only, unused)
  gemm_p_kv<<<dim3(5, 12, 2), b256, 0, stream>>>(ehs_bf, Wk_bf, bk, k_f, Wv_bf, bv, v_f,
                                                 640, 1536, 2048);
  // build attn images
  prep_kv<<<dim3(4, 24, 2), b256, 0, stream>>>(k_f, v_f, bk, bv, kimg, vimg);
  // Q projection
  gemm_p<ushort><<<dim3(128, 12), b256, 0, stream>>>(hs_bf, Wq_bf, bq, q_bf, 16384, 1536, 1536);
  // MFMA component-softmax attention
  attn_v4<<<dim3(32, 24, 2), b256, 0, stream>>>(q_bf, kimg, vimg, ao_bf);
  // output projection -> d_out (f32)
  gemm_p<float><<<dim3(128, 12), b256, 0, stream>>>(ao_bf, Wo_bf, bo, out, 16384, 1536, 1536);
}